// Round 15
// baseline (196.144 us; speedup 1.0000x reference)
//
#include <hip/hip_runtime.h>

// LocEncoder fused, round 15: balanced 256-block partition with coalesced
// LDS-sorted flush; aggregate split into two half-dispatches to force
// profile decomposition of the stubborn ~85-us hidden partition cost.
//
//   h1 = relu(u[src] - w[dst]),  u/w precomputed fp16 (round-5 algebra)
//
//  k1 precompute (1024 x 256): wave-per-2-nodes VALU -> u16,w16 [N,64] fp16
//  k2 partition (256 x 256, ~38 KB LDS, exactly 1 block/CU -> zero ceil
//      imbalance): per 6272-edge batch: pass1 hist(1563 bins)+scan+offsT,
//      pass2 re-read (L2-hot) + LDS scatter into a bucket-sorted 25-KB
//      stage, then FULLY-COALESCED contiguous flush (no scattered global
//      stores -- the suspected 3x cost of every partition since R6).
//  k3/k4 aggregate (2 x 782 blocks x 256, ~14 KB LDS): R14's proven fp16
//      MFMA register-max core; run table now 256 entries (8-step search,
//      4-wave scan). Split is intentionally 2 dispatches (~44 us each) so
//      any partition cost >44 us surfaces in the next profile.

#define N_NODES 100000
#define N_EDGES 1600000
#define NB2   1563    // dst buckets (dst >> 6), 64 nodes each
#define PNBLK 256     // partition blocks
#define PBATCH 6272   // edges per partition block (mult of 4; 256*6272 >= E)
#define SCAP2 1280    // staged edges per bucket (mean 1024, +8 sigma)

typedef _Float16 half8 __attribute__((ext_vector_type(8)));
typedef float float4v __attribute__((ext_vector_type(4)));

__device__ inline int wave_incl_scan(int v, int lane) {
#pragma unroll
    for (int d = 1; d < 64; d <<= 1) {
        const int t = __shfl_up(v, d);
        if (lane >= d) v += t;
    }
    return v;
}

// ---- k1: u/w precompute, 2 nodes per wave-iteration ----
__global__ __launch_bounds__(256) void precompute_kernel(
    const float* __restrict__ x, const float* __restrict__ pos,
    const float* __restrict__ W1, const float* __restrict__ b1,
    _Float16* __restrict__ u16, _Float16* __restrict__ w16)
{
    const int lane = threadIdx.x & 63;
    float w1c[16];
#pragma unroll
    for (int k = 0; k < 16; ++k) w1c[k] = W1[k * 64 + lane];
    const float b1c = b1[lane];

    const int waveId = blockIdx.x * 4 + (threadIdx.x >> 6);
    const int step   = 1024 * 4 * 2;

    for (int nd = waveId * 2; nd < N_NODES; nd += step) {
        const int nA = nd, nB = nd + 1;  // N_NODES even -> nB valid
        float mA = 0.f, mB = 0.f;
        if (lane < 13) {
            mA = x[nA * 13 + lane];
            mB = x[nB * 13 + lane];
        } else if (lane < 16) {
            mA = pos[nA * 3 + (lane - 13)];
            mB = pos[nB * 3 + (lane - 13)];
        }

        float aA = b1c, wA = 0.f, aB = b1c, wB = 0.f;
#pragma unroll
        for (int k = 0; k < 13; ++k) {
            aA = fmaf(__shfl(mA, k), w1c[k], aA);
            aB = fmaf(__shfl(mB, k), w1c[k], aB);
        }
#pragma unroll
        for (int k = 13; k < 16; ++k) {
            const float pA = __shfl(mA, k), pB = __shfl(mB, k);
            aA = fmaf(pA, w1c[k], aA);  wA = fmaf(pA, w1c[k], wA);
            aB = fmaf(pB, w1c[k], aB);  wB = fmaf(pB, w1c[k], wB);
        }
        u16[nA * 64 + lane] = (_Float16)aA;
        w16[nA * 64 + lane] = (_Float16)wA;
        u16[nB * 64 + lane] = (_Float16)aB;
        w16[nB * 64 + lane] = (_Float16)wB;
    }
}

// ---- k2: balanced partition, LDS-sorted coalesced flush ----
__global__ __launch_bounds__(256) void partition_kernel(
    const int* __restrict__ ei,        // [2,E]
    int* __restrict__ offsT,           // [NB2+1][PNBLK] transposed
    int* __restrict__ blockSorted)     // [E] flat; region blk*PBATCH, compact
{
    __shared__ int stage[PBATCH];                // 25,088 B
    __shared__ int hist[NB2], offc[NB2];         // 12,504 B
    __shared__ int csumP[25];

    const int tid  = threadIdx.x;
    const int lane = tid & 63;
    const int wv   = tid >> 6;
    const int blk  = blockIdx.x;
    const int e0   = blk * PBATCH;
    const int nn   = (N_EDGES - e0) < PBATCH ? (N_EDGES - e0) : PBATCH;  // %4==0

    for (int i = tid; i < NB2; i += 256) hist[i] = 0;
    __syncthreads();

    // pass 1: histogram (int4 reads)
    const int4* d4p = (const int4*)(ei + N_EDGES + e0);
    const int4* s4p = (const int4*)(ei + e0);
    const int nq = nn >> 2;
    for (int i = tid; i < nq; i += 256) {
        const int4 d4 = d4p[i];
        atomicAdd(&hist[d4.x >> 6], 1);
        atomicAdd(&hist[d4.y >> 6], 1);
        atomicAdd(&hist[d4.z >> 6], 1);
        atomicAdd(&hist[d4.w >> 6], 1);
    }
    __syncthreads();

    // exclusive scan hist[0..NB2) -> offc (25 chunks of 64)
    for (int c = wv; c < 25; c += 4) {
        const int idx = c * 64 + lane;
        const int val = (idx < NB2) ? hist[idx] : 0;
        const int inc = wave_incl_scan(val, lane);
        if (idx < NB2) offc[idx] = inc - val;
        if (lane == 63) csumP[c] = inc;
    }
    __syncthreads();
    if (tid == 0) {
        int a = 0;
#pragma unroll
        for (int c = 0; c < 25; ++c) { const int t = csumP[c]; csumP[c] = a; a += t; }
    }
    __syncthreads();
    for (int c = wv; c < 25; c += 4) {
        const int idx = c * 64 + lane;
        if (idx < NB2) offc[idx] += csumP[c];
    }
    __syncthreads();

    // offsets out (transposed), keep scatter cursors in offc
    for (int b = tid; b < NB2; b += 256) offsT[b * PNBLK + blk] = offc[b];
    if (tid == 0) offsT[NB2 * PNBLK + blk] = nn;  // sentinel row
    __syncthreads();

    // pass 2: re-read (L2-hot) + LDS scatter into bucket-sorted stage
    for (int i = tid; i < nq; i += 256) {
        const int4 s4 = s4p[i];
        const int4 d4 = d4p[i];
        int p;
        p = atomicAdd(&offc[d4.x >> 6], 1); stage[p] = (s4.x << 6) | (d4.x & 63);
        p = atomicAdd(&offc[d4.y >> 6], 1); stage[p] = (s4.y << 6) | (d4.y & 63);
        p = atomicAdd(&offc[d4.z >> 6], 1); stage[p] = (s4.z << 6) | (d4.z & 63);
        p = atomicAdd(&offc[d4.w >> 6], 1); stage[p] = (s4.w << 6) | (d4.w & 63);
    }
    __syncthreads();

    // coalesced contiguous flush (full-line writes only)
    for (int i = tid; i < nn; i += 256)
        blockSorted[e0 + i] = stage[i];
}

// ---- k3/k4: bucket aggregate (R14 core; 256-run table; half-grid) ----
__global__ __launch_bounds__(256, 4) void aggregate_kernel(
    const _Float16* __restrict__ u16,  // [N,64] fp16
    const _Float16* __restrict__ w16,  // [N,64] fp16
    const float* __restrict__ W2,      // [64,64]
    const float* __restrict__ b2,      // [64]
    const int*   __restrict__ offsT,   // [NB2+1][PNBLK]
    const int*   __restrict__ blockSorted,  // [E]
    float*       __restrict__ out,     // [N,64]
    int bucketBase)
{
    __shared__ int staged[SCAP2];       // 5,120 B packed edges
    __shared__ int sortedL[SCAP2];      // 5,120 B src, grouped by node
    __shared__ int E[PNBLK], G[PNBLK];  // 2,048 B
    __shared__ int hist[64], nstart[64], hoff[64];
    __shared__ int csum[4];
    __shared__ int totT;

    const int tid  = threadIdx.x;
    const int lane = tid & 63;
    const int wv   = tid >> 6;
    const int q = lane >> 4, n = lane & 15;
    const int b = blockIdx.x + bucketBase;
    const int node0 = b * 64;

    // W2 B-frags (fp16) + bias
    half8 w2f[2][4];
#pragma unroll
    for (int s = 0; s < 2; ++s)
#pragma unroll
        for (int t = 0; t < 4; ++t)
#pragma unroll
            for (int j = 0; j < 8; ++j)
                w2f[s][t][j] = (_Float16)W2[(s * 32 + q * 8 + j) * 64 + (n + 16 * t)];
    float b2c[4];
#pragma unroll
    for (int t = 0; t < 4; ++t) b2c[t] = b2[n + 16 * t];

    if (tid < 64) hist[tid] = 0;

    // p1: run table (256 runs, one per thread), exact 4-wave scan
    {
        const int lo = offsT[b * PNBLK + tid];
        const int hi = offsT[(b + 1) * PNBLK + tid];
        const int len = hi - lo;
        G[tid] = tid * PBATCH + lo;
        const int inc = wave_incl_scan(len, lane);
        E[tid] = inc;
        if (lane == 63) csum[wv] = inc;
        __syncthreads();
        if (tid == 0) {
            int a = 0;
#pragma unroll
            for (int c = 0; c < 4; ++c) { const int t = csum[c]; csum[c] = a; a += t; }
            totT = a;
        }
        __syncthreads();
        E[tid] += csum[wv] - len;  // exclusive prefix
    }
    __syncthreads();

    int T = totT; T = T < SCAP2 ? T : SCAP2;

    // p2: gather bucket edges into staged + 64-bin node histogram
    for (int i = tid; i < T; i += 256) {
        int lo = 0, hi = PNBLK - 1;
#pragma unroll
        for (int s = 0; s < 8; ++s) {  // 2^8 = 256
            const int mid = (lo + hi + 1) >> 1;
            if (E[mid] <= i) lo = mid; else hi = mid - 1;
        }
        const int w = blockSorted[G[lo] + (i - E[lo])];
        staged[i] = w;
        atomicAdd(&hist[w & 63], 1);
    }
    __syncthreads();

    // p3: scan hist(64) by wave 0 -> nstart; counting-sort into sortedL
    if (wv == 0) {
        const int v = hist[lane];
        const int inc = wave_incl_scan(v, lane);
        nstart[lane] = inc - v;
        hoff[lane]   = inc - v;
    }
    __syncthreads();
    for (int i = tid; i < T; i += 256) {
        const int w = staged[i];
        const int p = atomicAdd(&hoff[w & 63], 1);
        sortedL[p] = w >> 6;
    }
    __syncthreads();

    // p4: per-node register-max fp16 MFMA (pairs; gathers in flight first)
    const half8 zero8 = {0, 0, 0, 0, 0, 0, 0, 0};

    auto compute = [&](int node, int2 sd, int src,
                       half8 ulo, half8 uhi, half8 wl, half8 wh) {
        float vmax[4] = {0.f, 0.f, 0.f, 0.f};  // 0-init == relu + empty=0
        int base = 0;
        while (true) {
            const int rows = (sd.y - base) < 16 ? (sd.y - base) : 16;
            if (rows > 0) {
                const half8 alo = __builtin_elementwise_max(ulo - wl, zero8);
                const half8 ahi = __builtin_elementwise_max(uhi - wh, zero8);
                float4v c2[4];
#pragma unroll
                for (int t = 0; t < 4; ++t) {
                    c2[t] = __builtin_amdgcn_mfma_f32_16x16x32_f16(
                        alo, w2f[0][t], (float4v){0.f, 0.f, 0.f, 0.f}, 0, 0, 0);
                    c2[t] = __builtin_amdgcn_mfma_f32_16x16x32_f16(
                        ahi, w2f[1][t], c2[t], 0, 0, 0);
                }
#pragma unroll
                for (int r = 0; r < 4; ++r) {
                    const int row = q * 4 + r;
#pragma unroll
                    for (int t = 0; t < 4; ++t) {
                        const float v = c2[t][r] + b2c[t];
                        if (row < rows) vmax[t] = fmaxf(vmax[t], v);
                    }
                }
            }
            base += 16;
            if (base >= sd.y) break;
            const int r2 = (sd.y - base) < 16 ? (sd.y - base) : 16;
            src = (n < r2) ? sortedL[sd.x + base + n] : 0;
            ulo = *(const half8*)(u16 + src * 64 + q * 8);
            uhi = *(const half8*)(u16 + src * 64 + 32 + q * 8);
        }
#pragma unroll
        for (int t = 0; t < 4; ++t) {
            vmax[t] = fmaxf(vmax[t], __shfl_xor(vmax[t], 16));
            vmax[t] = fmaxf(vmax[t], __shfl_xor(vmax[t], 32));
        }
        float v = vmax[0];
        v = (q == 1) ? vmax[1] : v;
        v = (q == 2) ? vmax[2] : v;
        v = (q == 3) ? vmax[3] : v;
        if (node < N_NODES) out[node * 64 + lane] = v;
    };

    const int nlbase = wv * 16;
#pragma unroll 1
    for (int g = 0; g < 16; g += 2) {
        const int nlA = nlbase + g, nlB = nlA + 1;
        const int nA = node0 + nlA, nB = node0 + nlB;
        const int2 sdA = {nstart[nlA], hist[nlA]};
        const int2 sdB = {nstart[nlB], hist[nlB]};
        const int nAc = nA < (N_NODES - 1) ? nA : (N_NODES - 1);  // clamp loads
        const int nBc = nB < (N_NODES - 1) ? nB : (N_NODES - 1);

        const int rA = sdA.y < 16 ? sdA.y : 16;
        const int rB = sdB.y < 16 ? sdB.y : 16;
        const int srcA = (n < rA) ? sortedL[sdA.x + n] : 0;
        const int srcB = (n < rB) ? sortedL[sdB.x + n] : 0;

        // both nodes' gathers in flight before either compute
        const half8 ulA = *(const half8*)(u16 + srcA * 64 + q * 8);
        const half8 uhA = *(const half8*)(u16 + srcA * 64 + 32 + q * 8);
        const half8 wlA = *(const half8*)(w16 + nAc * 64 + q * 8);
        const half8 whA = *(const half8*)(w16 + nAc * 64 + 32 + q * 8);
        const half8 ulB = *(const half8*)(u16 + srcB * 64 + q * 8);
        const half8 uhB = *(const half8*)(u16 + srcB * 64 + 32 + q * 8);
        const half8 wlB = *(const half8*)(w16 + nBc * 64 + q * 8);
        const half8 whB = *(const half8*)(w16 + nBc * 64 + 32 + q * 8);

        compute(nA, sdA, srcA, ulA, uhA, wlA, whA);
        compute(nB, sdB, srcB, ulB, uhB, wlB, whB);
    }
}

extern "C" void kernel_launch(void* const* d_in, const int* in_sizes, int n_in,
                              void* d_out, int out_size, void* d_ws, size_t ws_size,
                              hipStream_t stream) {
    const float* x   = (const float*)d_in[0];
    const float* pos = (const float*)d_in[1];
    const float* W1  = (const float*)d_in[2];
    const float* b1  = (const float*)d_in[3];
    const float* W2  = (const float*)d_in[4];
    const float* b2  = (const float*)d_in[5];
    const int*   ei  = (const int*)d_in[6];

    char* ws = (char*)d_ws;
    int* blockSorted = (int*)(ws + 0);          // 6,400,000 B [E]
    int* offsT       = (int*)(ws + 6400000);    // 1,601,536 B [1564][256]
    _Float16* u16 = (_Float16*)(ws + 8001536);  // 12.8 MB
    _Float16* w16 = (_Float16*)(ws + 20801536); // 12.8 MB

    precompute_kernel<<<1024, 256, 0, stream>>>(x, pos, W1, b1, u16, w16);
    partition_kernel<<<PNBLK, 256, 0, stream>>>(ei, offsT, blockSorted);
    // two half-dispatches: forces partition to surface in top-5 if >~44 us
    aggregate_kernel<<<782, 256, 0, stream>>>(
        u16, w16, W2, b2, offsT, blockSorted, (float*)d_out, 0);
    aggregate_kernel<<<781, 256, 0, stream>>>(
        u16, w16, W2, b2, offsT, blockSorted, (float*)d_out, 782);
}